// Round 2
// 338.338 us; speedup vs baseline: 1.0872x; 1.0872x over previous
//
#include <hip/hip_runtime.h>
#include <stdint.h>

#define B_ 32
#define T_ 4096
#define C_ 256
#define N_ (T_*C_)            // 1<<20 elements per sample
#define NB 8192               // top 13 bits of |x| bit pattern: bits[30:18]

// ---- workspace layout (bytes) ----
#define HIST_BYTES (B_*NB*4)             // 1 MB (global hist stays u32[8192] per sample)
#define USUM_OFF   (HIST_BYTES)          // 32 floats
#define THR_OFF    (USUM_OFF + 128)      // 32 floats

typedef float f32x4 __attribute__((ext_vector_type(4)));

// K1: fused uncertainty partial sums + 13-bit histogram of |s|.
// grid = 2048 blocks (64 per sample) x 512 threads; block handles 4096 float4
// = 16384 floats = 64 tokens per tensor.
// Hot loop has NO cross-lane ops and NO lgkmcnt-dependent chains:
// per-lane partials go to LDS, token reduce happens once at block end.
// Histogram packed 2 bins/word in u16 halves (max 16384/bin per block -> no overflow).
__global__ __launch_bounds__(512, 8) void k1_uncert_hist(
    const float* __restrict__ s, const float* __restrict__ t,
    float* __restrict__ usum, unsigned* __restrict__ ghist)
{
    __shared__ unsigned lhist[4096];          // 16 KB packed u16x2
    __shared__ float part[64*65];             // 16.6 KB, 65-stride = conflict-free reduce
    __shared__ float wu[8];
    const int tid = threadIdx.x;
    #pragma unroll
    for (int k = tid; k < 4096; k += 512) lhist[k] = 0;
    __syncthreads();

    const int b = blockIdx.x >> 6;                    // 64 blocks per sample
    const size_t base4 = (size_t)blockIdx.x * 4096;   // float4 units
    const f32x4* s4 = (const f32x4*)s + base4;
    const f32x4* t4 = (const f32x4*)t + base4;
    const int lane = tid & 63, wid = tid >> 6;

    // iter it: i = it*1024 + wid*128 + lane; tokens it*16+wid*2 (+1)
    int i = wid*128 + lane;
    f32x4 a0 = s4[i];
    f32x4 a1 = s4[i + 64];
    f32x4 c0 = __builtin_nontemporal_load(t4 + i);      // t never re-read: keep s in L3
    f32x4 c1 = __builtin_nontemporal_load(t4 + i + 64);

    #pragma unroll
    for (int it = 0; it < 4; ++it) {
        f32x4 b0, b1, d0, d1;
        const int inext = i + 1024;
        if (it < 3) {                                   // depth-2 rotation prefetch
            b0 = s4[inext];
            b1 = s4[inext + 64];
            d0 = __builtin_nontemporal_load(t4 + inext);
            d1 = __builtin_nontemporal_load(t4 + inext + 64);
        }

        float dx = a0.x-c0.x, dy = a0.y-c0.y, dz = a0.z-c0.z, dw = a0.w-c0.w;
        float sum0 = dx*dx + dy*dy + dz*dz + dw*dw;
        float ex = a1.x-c1.x, ey = a1.y-c1.y, ez = a1.z-c1.z, ew = a1.w-c1.w;
        float sum1 = ex*ex + ey*ey + ez*ez + ew*ew;

        // packed histogram: word = bits[30:19], half = bit18
        {
            unsigned u;
            u = __float_as_uint(a0.x); atomicAdd(&lhist[(u>>19)&0xFFF], 1u << (((u>>18)&1u)<<4));
            u = __float_as_uint(a0.y); atomicAdd(&lhist[(u>>19)&0xFFF], 1u << (((u>>18)&1u)<<4));
            u = __float_as_uint(a0.z); atomicAdd(&lhist[(u>>19)&0xFFF], 1u << (((u>>18)&1u)<<4));
            u = __float_as_uint(a0.w); atomicAdd(&lhist[(u>>19)&0xFFF], 1u << (((u>>18)&1u)<<4));
            u = __float_as_uint(a1.x); atomicAdd(&lhist[(u>>19)&0xFFF], 1u << (((u>>18)&1u)<<4));
            u = __float_as_uint(a1.y); atomicAdd(&lhist[(u>>19)&0xFFF], 1u << (((u>>18)&1u)<<4));
            u = __float_as_uint(a1.z); atomicAdd(&lhist[(u>>19)&0xFFF], 1u << (((u>>18)&1u)<<4));
            u = __float_as_uint(a1.w); atomicAdd(&lhist[(u>>19)&0xFFF], 1u << (((u>>18)&1u)<<4));
        }

        // per-lane partials -> LDS (no waits, no syncs, conflict-free)
        const int tk = it*16 + wid*2;
        part[tk*65 + lane]     = sum0;
        part[(tk+1)*65 + lane] = sum1;

        if (it < 3) { a0 = b0; a1 = b1; c0 = d0; c1 = d1; }
        i = inext;
    }
    __syncthreads();

    // block-end token reduce: thread -> token tid>>3, chunk tid&7 (8 floats)
    {
        const int tok = tid >> 3, q = tid & 7;
        const float* pp = &part[tok*65 + q*8];
        float ps = pp[0]+pp[1]+pp[2]+pp[3]+pp[4]+pp[5]+pp[6]+pp[7];
        ps += __shfl_xor(ps, 1, 64);
        ps += __shfl_xor(ps, 2, 64);
        ps += __shfl_xor(ps, 4, 64);                 // 8-lane group: full token sum
        // clip(2*mean,0,1) = min(sum/128,1)
        float u = fminf(ps * (1.0f/128.0f), 1.0f);
        // xor over bits 3..5 picks exactly ONE representative lane per 8-lane
        // group -> sums the wave's 8 distinct tokens exactly once each.
        u += __shfl_xor(u, 8, 64);
        u += __shfl_xor(u, 16, 64);
        u += __shfl_xor(u, 32, 64);
        if (lane == 0) wu[wid] = u;
    }
    __syncthreads();
    if (tid == 0) {
        float a = 0.f;
        #pragma unroll
        for (int w = 0; w < 8; ++w) a += wu[w];
        atomicAdd(&usum[b], a);
    }

    // drain packed hist -> global u32 hist
    unsigned* gh = ghist + (size_t)b * NB;
    #pragma unroll
    for (int w = tid; w < 4096; w += 512) {
        const unsigned pc = lhist[w];
        if (pc) {
            const unsigned lo = pc & 0xFFFFu, hi = pc >> 16;
            if (lo) atomicAdd(&gh[2*w],   lo);
            if (hi) atomicAdd(&gh[2*w+1], hi);
        }
    }
}

// K2: per-sample threshold from histogram; fully parallel scan + owner search.
// grid = 32 blocks x 256 threads.
__global__ __launch_bounds__(256) void k2_thresh(
    const unsigned* __restrict__ ghist, const float* __restrict__ usum,
    const float* __restrict__ risk, float* __restrict__ thr)
{
    __shared__ unsigned lh[NB];
    __shared__ unsigned sc[256];
    __shared__ float res[2];
    const int b = blockIdx.x, tid = threadIdx.x;
    const unsigned* gh = ghist + (size_t)b * NB;
    for (int j = tid; j < NB; j += 256) lh[j] = gh[j];   // coalesced
    __syncthreads();

    unsigned p = 0;
    #pragma unroll
    for (int k = 0; k < 32; ++k) p += lh[tid*32 + k];
    sc[tid] = p;
    __syncthreads();
    // Hillis-Steele inclusive scan over 256
    #pragma unroll
    for (int d = 1; d < 256; d <<= 1) {
        unsigned v = (tid >= d) ? sc[tid - d] : 0u;
        __syncthreads();
        sc[tid] += v;
        __syncthreads();
    }
    const unsigned incl = sc[tid];
    const unsigned excl = incl - p;

    // every thread computes the ranks identically
    const float distrust = usum[b] * fmaxf(1.f, risk[b]) * (1.0f/(float)T_);
    const double pq  = 0.99 - 0.09 * (double)distrust;
    const double pos = pq * (double)(N_ - 1);
    const unsigned i0 = (unsigned)pos;
    const float g = (float)(pos - (double)i0);

    #pragma unroll
    for (int r = 0; r < 2; ++r) {
        const unsigned rk = i0 + (unsigned)r;
        if (excl <= rk && rk < incl) {               // exactly one owner
            unsigned cum = excl, cnt = 1;
            int bin = tid*32 + 31;
            #pragma unroll
            for (int k = 0; k < 32; ++k) {
                const unsigned c = lh[tid*32 + k];
                if (cum + c > rk) { bin = tid*32 + k; cnt = c; break; }
                cum += c;
            }
            const float lo = __uint_as_float((unsigned)bin << 18);
            const float hi = __uint_as_float((unsigned)(bin + 1) << 18);
            const unsigned j = rk - cum;             // 0-based rank within bin
            res[r] = lo + ((float)(j + 1) / (float)(cnt + 1)) * (hi - lo);
        }
    }
    __syncthreads();
    if (tid == 0) thr[b] = res[0] + g * (res[1] - res[0]);
}

// K3: clip. grid = 4096 blocks x 256 threads, 8 independent float4 per thread.
__global__ __launch_bounds__(256) void k3_clip(
    const float* __restrict__ s, const float* __restrict__ thr,
    float* __restrict__ out)
{
    const int bid = blockIdx.x;
    const int b = bid >> 7;                          // 128 blocks per sample
    const float t = thr[b];
    const size_t base = (size_t)bid * 2048 + threadIdx.x;
    const f32x4* s4 = (const f32x4*)s;
    f32x4* o4 = (f32x4*)out;

    f32x4 v[8];
    #pragma unroll
    for (int k = 0; k < 8; ++k) v[k] = s4[base + (size_t)k*256];
    #pragma unroll
    for (int k = 0; k < 8; ++k) {
        f32x4 a = v[k];
        a.x = fminf(fmaxf(a.x, -t), t);
        a.y = fminf(fmaxf(a.y, -t), t);
        a.z = fminf(fmaxf(a.z, -t), t);
        a.w = fminf(fmaxf(a.w, -t), t);
        __builtin_nontemporal_store(a, o4 + base + (size_t)k*256);
    }
}

extern "C" void kernel_launch(void* const* d_in, const int* in_sizes, int n_in,
                              void* d_out, int out_size, void* d_ws, size_t ws_size,
                              hipStream_t stream) {
    const float* s    = (const float*)d_in[0];
    const float* t    = (const float*)d_in[1];
    const float* risk = (const float*)d_in[2];
    float* out = (float*)d_out;
    char* ws = (char*)d_ws;

    unsigned* hist = (unsigned*)(ws);
    float*    usum = (float*)(ws + USUM_OFF);
    float*    thr  = (float*)(ws + THR_OFF);

    // zero histogram + usum (ws is poisoned 0xAA before each timed launch)
    hipMemsetAsync(ws, 0, HIST_BYTES + 256, stream);

    k1_uncert_hist<<<2048, 512, 0, stream>>>(s, t, usum, hist);
    k2_thresh<<<B_, 256, 0, stream>>>(hist, usum, risk, thr);
    k3_clip<<<4096, 256, 0, stream>>>(s, thr, out);
}